// Round 15
// baseline (390.840 us; speedup 1.0000x reference)
//
#include <hip/hip_runtime.h>
#include <hip/hip_bf16.h>

#define TAU_INV 2.0f
#define R_ 5
#define NU 50000
#define NM 20000
#define EDGES 100000
#define F_ 4
#define D_ 16
#define DR 64
#define OUT_ 64

__device__ __forceinline__ float dot4(float4 a, float4 b) {
    return a.x * b.x + a.y * b.y + a.z * b.z + a.w * b.w;
}

__device__ __forceinline__ ushort f2bf(float x) {
    __hip_bfloat16 h = __float2bfloat16(x);
    return *reinterpret_cast<ushort*>(&h);
}

__device__ __forceinline__ float bf2f(ushort u) {
    uint v = ((uint)u) << 16;
    return *reinterpret_cast<float*>(&v);
}

// FUSED: 4 edges per wave, 16 lanes per edge. Phase 1 = gating weight w (as R12).
// Phase 2 = message matvec am/au reusing the L2-hot rf_k/ufk/mfk lines, stored
// as one 64B bf16-packed line per edge. Kills the entire second edge pass over
// rfeat (128 MB) and its ~1.2M random gather lines.
__global__ __launch_bounds__(256) void k_edge_w(
    const float* __restrict__ ufk, const float* __restrict__ mfk,
    const float* __restrict__ ufs, const float* __restrict__ mfs,
    const float* __restrict__ rfeat, const float* __restrict__ proto,
    const float* __restrict__ eta, const int* __restrict__ eu,
    const int* __restrict__ em, const int* __restrict__ kp,
    const float* __restrict__ nwf, const float* __restrict__ rwf,
    const float* __restrict__ nwr, const float* __restrict__ rwr,
    float* __restrict__ wbuf, float* __restrict__ nrm_u, float* __restrict__ nrm_m,
    uint* __restrict__ msg)
{
    const int tid = threadIdx.x;
    const int wv = tid >> 6, l = tid & 63;
    const int g16 = l >> 4;          // edge slot within wave
    const int j   = l & 15;          // lane within 16-lane group
    const int r = blockIdx.y;
    const int rE = r * EDGES;
    const int e = (blockIdx.x * 4 + wv) * 4 + g16;   // always < EDGES (100000 = 6250*16)
    const int idx = rE + e;
    const int u = eu[idx], m = em[idx];
    const int kk = kp[0];

    // ---- matvec weights for (o=l&15, q=l>>4), loop-invariant (R12 mapping) ----
    const int o = j, q = g16;
    const float4* pwf = (const float4*)(rwf + (size_t)r * 1024 + o * 64 + q * 16);
    const float4* pwr = (const float4*)(rwr + (size_t)r * 1024 + o * 64 + q * 16);
    const float4 wfA = pwf[0], wfB = pwf[1], wfC = pwf[2], wfD = pwf[3];
    const float4 wrA = pwr[0], wrB = pwr[1], wrC = pwr[2], wrD = pwr[3];
    const float4 nf = *(const float4*)(nwf + r * 256 + o * 16 + q * 4);
    const float4 nr = *(const float4*)(nwr + r * 256 + o * 16 + q * 4);

    // ======== phase 1: gating weight (identical math to R12) ========
    const float4 pu = ((const float4*)(ufs + (size_t)(r * NU + u) * 64))[j];
    const float4 pm = ((const float4*)(mfs + (size_t)(r * NM + m) * 64))[j];
    float p = dot4(pu, pm);
    p += __shfl_xor(p, 1); p += __shfl_xor(p, 2);
    const float es = expf(p * TAU_INV);
    float dsim = es;
    dsim += __shfl_xor(dsim, 4); dsim += __shfl_xor(dsim, 8);

    const int jc = j & 3;
    const float4 u4 = ((const float4*)(ufk + (size_t)(r * NU + u) * 16))[jc];
    const float4 m4 = ((const float4*)(mfk + (size_t)(r * NM + m) * 16))[jc];
    float su = dot4(u4, u4), sm = dot4(m4, m4), sd = dot4(u4, m4);
    su += __shfl_xor(su, 1); su += __shfl_xor(su, 2);
    sm += __shfl_xor(sm, 1); sm += __shfl_xor(sm, 2);
    sd += __shfl_xor(sd, 1); sd += __shfl_xor(sd, 2);
    const float nsim = expf(sd / (fmaxf(sqrtf(su), 1e-12f) * fmaxf(sqrtf(sm), 1e-12f)) * TAU_INV);

    const float4* rf4 = (const float4*)(rfeat + (size_t)idx * 256);
    const float4* pr4 = (const float4*)proto;
    const int base = (j >> 2) * 16 + (j & 3) * 4;
    float ap = 0.f;
#pragma unroll
    for (int t = 0; t < 4; ++t)
        ap += dot4(rf4[base + t], pr4[base + t]);
    ap += __shfl_xor(ap, 1); ap += __shfl_xor(ap, 2);
    const float ea = expf(ap * TAU_INV);
    float dan = ea;
    dan += __shfl_xor(dan, 4); dan += __shfl_xor(dan, 8);
    const float adk = __shfl(ap, (l & 48) | (kk << 2));
    const float na = expf(adk * TAU_INV);

    const float gt = 1.0f / (1.0f + expf(-eta[idx]));
    const float w = gt * (na / dan) + (1.0f - gt) * (nsim / dsim);

    if (j == 0) {
        wbuf[idx] = w;
        atomicAdd(&nrm_u[u], w);
        atomicAdd(&nrm_m[m], w);
    }
    // (all lanes re-converge here)

    // ======== phase 2: per-edge matvec from L2-hot lines ========
    float amv[4], auv[4];
#pragma unroll
    for (int s = 0; s < 4; ++s) {
        const int e_s   = (blockIdx.x * 4 + wv) * 4 + s;
        const int idx_s = rE + e_s;
        const int u_s = __shfl(u, s * 16);   // full convergence
        const int m_s = __shfl(m, s * 16);

        // broadcast re-reads (lines just fetched by phase 1 -> L2-hot)
        const float4* rk = (const float4*)(rfeat + ((size_t)idx_s * 4 + kk) * 64) + q * 4;
        const float4 a0 = rk[0], a1 = rk[1], a2 = rk[2], a3 = rk[3];
        const float4 uf = ((const float4*)(ufk + (size_t)(r * NU + u_s) * 16))[q];
        const float4 mf = ((const float4*)(mfk + (size_t)(r * NM + m_s) * 16))[q];

        float am = dot4(a0, wfA) + dot4(a1, wfB) + dot4(a2, wfC) + dot4(a3, wfD)
                 + dot4(uf, nf);
        float au = dot4(a0, wrA) + dot4(a1, wrB) + dot4(a2, wrC) + dot4(a3, wrD)
                 + dot4(mf, nr);
        am += __shfl_xor(am, 16); am += __shfl_xor(am, 32);
        au += __shfl_xor(au, 16); au += __shfl_xor(au, 32);
        amv[s] = am; auv[s] = au;
    }
    // store own group's edge: one 64B line per edge (lane o writes packed uint)
    const uint pk = (uint)f2bf(amv[g16]) | ((uint)f2bf(auv[g16]) << 16);
    msg[(size_t)idx * 16 + o] = pk;
}

// Scatter pass: per edge read its 64B packed message + wn, two atomic RMWs.
// 2 edges per 64-lane wave iteration (lanes 0-15: am->ipre, 16-31: au->upre,
// 32-63: same for second edge). 8 edges per wave.
__global__ __launch_bounds__(256) void k_scatter(
    const int* __restrict__ eu, const int* __restrict__ em,
    const float* __restrict__ wbuf, const float* __restrict__ nrm_u,
    const float* __restrict__ nrm_m, const uint* __restrict__ msg,
    float* __restrict__ upre, float* __restrict__ ipre, float* __restrict__ dist_out)
{
    const int tid = threadIdx.x;
    const int wv = tid >> 6, l = tid & 63;
    const int o = l & 15;
    const int r = blockIdx.y;
    const int rE = r * EDGES;
    const int ebase = (blockIdx.x * 4 + wv) * 8;   // EDGES = 3125*32 exact

    float wnsave = 0.f;
#pragma unroll
    for (int j = 0; j < 8; j += 2) {
        const int e0 = ebase + j, e1 = e0 + 1;
        const int u0 = eu[rE + e0], m0 = em[rE + e0];
        const int u1 = eu[rE + e1], m1 = em[rE + e1];
        const float wn0 = wbuf[rE + e0] / sqrtf(nrm_u[u0] * nrm_m[m0]);
        const float wn1 = wbuf[rE + e1] / sqrtf(nrm_u[u1] * nrm_m[m1]);
        if (l == j)     wnsave = wn0;
        if (l == j + 1) wnsave = wn1;

        const int  half = l >> 5;
        const int  eh   = half ? e1 : e0;
        const uint pk   = msg[(size_t)(rE + eh) * 16 + o];
        const float wnh = half ? wn1 : wn0;
        const bool up   = (l & 31) >= 16;         // upper 16 of each 32: au->upre
        const float val = bf2f(up ? (ushort)(pk >> 16) : (ushort)(pk & 0xffff)) * wnh;
        const int  uh   = half ? u1 : u0;
        const int  mh   = half ? m1 : m0;
        float* basep = up ? &upre[(size_t)uh * 16 + o] : &ipre[(size_t)mh * 16 + o];
        atomicAdd(basep, val);
    }
    if (l < 8)
        dist_out[rE + ebase + l] = wnsave;   // coalesced 32B store per wave
}

// Fused leaky-relu + (N,16) x (16,64) FC for both tables. (unchanged)
__global__ __launch_bounds__(256) void k_fc(
    const float* __restrict__ upre, const float* __restrict__ ipre,
    const float* __restrict__ uw, const float* __restrict__ ub,
    const float* __restrict__ iw, const float* __restrict__ ib,
    float* __restrict__ out_u, float* __restrict__ out_i)
{
    const int tid = threadIdx.x;
    const int n = blockIdx.x * 4 + (tid >> 6);
    if (n >= NU + NM) return;
    const int o = tid & 63;
    const float* pre; const float* W; const float* B; float* dst;
    if (n < NU) { pre = upre + (size_t)n * 16; W = uw; B = ub; dst = out_u + (size_t)n * 64; }
    else { int n2 = n - NU; pre = ipre + (size_t)n2 * 16; W = iw; B = ib; dst = out_i + (size_t)n2 * 64; }
    float acc = B[o];
#pragma unroll
    for (int d = 0; d < 16; d++) {
        float x = pre[d];
        x = x >= 0.f ? x : 0.1f * x;
        acc += x * W[o * 16 + d];
    }
    dst[o] = acc;
}

extern "C" void kernel_launch(void* const* d_in, const int* in_sizes, int n_in,
                              void* d_out, int out_size, void* d_ws, size_t ws_size,
                              hipStream_t stream) {
    const float* ufk  = (const float*)d_in[0];
    const float* mfk  = (const float*)d_in[1];
    const float* ufs  = (const float*)d_in[2];
    const float* mfs  = (const float*)d_in[3];
    const float* rfe  = (const float*)d_in[4];
    const float* pro  = (const float*)d_in[5];
    const float* eta  = (const float*)d_in[6];
    const float* nwf  = (const float*)d_in[7];
    const float* rwf  = (const float*)d_in[8];
    const float* nwr  = (const float*)d_in[9];
    const float* rwr  = (const float*)d_in[10];
    const float* uw   = (const float*)d_in[11];
    const float* ub   = (const float*)d_in[12];
    const float* iw   = (const float*)d_in[13];
    const float* ib   = (const float*)d_in[14];
    const int*   eu   = (const int*)d_in[15];
    const int*   em   = (const int*)d_in[16];
    const int*   kp   = (const int*)d_in[17];

    float* out    = (float*)d_out;
    float* out_u  = out;                         // NU*64
    float* out_i  = out + (size_t)NU * 64;       // NM*64
    float* out_d  = out_i + (size_t)NM * 64;     // R*E

    float* ws    = (float*)d_ws;
    float* nrm_u = ws;                           // NU
    float* nrm_m = nrm_u + NU;                   // NM
    float* upre  = nrm_m + NM;                   // NU*16
    float* ipre  = upre + (size_t)NU * 16;       // NM*16
    float* wbuf  = ipre + (size_t)NM * 16;       // R*E
    uint*  msg   = (uint*)(wbuf + (size_t)R_ * EDGES); // R*E*16 uints = 32 MB

    const size_t zeroN = (size_t)NU + NM + (size_t)NU * 16 + (size_t)NM * 16;
    hipMemsetAsync(d_ws, 0, zeroN * sizeof(float), stream);

    dim3 gW((EDGES + 15) / 16, R_);
    k_edge_w<<<gW, 256, 0, stream>>>(ufk, mfk, ufs, mfs, rfe, pro, eta, eu, em, kp,
                                     nwf, rwf, nwr, rwr, wbuf, nrm_u, nrm_m, msg);
    dim3 gS(EDGES / 32, R_);
    k_scatter<<<gS, 256, 0, stream>>>(eu, em, wbuf, nrm_u, nrm_m, msg,
                                      upre, ipre, out_d);
    k_fc<<<((NU + NM) + 3) / 4, 256, 0, stream>>>(upre, ipre, uw, ub, iw, ib, out_u, out_i);
}

// Round 16
// 272.567 us; speedup vs baseline: 1.4339x; 1.4339x over previous
//
#include <hip/hip_runtime.h>
#include <hip/hip_bf16.h>

#define TAU_INV 2.0f
#define R_ 5
#define NU 50000
#define NM 20000
#define EDGES 100000
#define F_ 4
#define D_ 16
#define DR 64
#define OUT_ 64
#define EPW 32  // edges per wave in k_edge_msg (2 MFMA 16-blocks)

typedef __attribute__((ext_vector_type(8))) short short8;  // 8 bf16
typedef __attribute__((ext_vector_type(4))) float f32x4;

__device__ __forceinline__ float dot4(float4 a, float4 b) {
    return a.x * b.x + a.y * b.y + a.z * b.z + a.w * b.w;
}

__device__ __forceinline__ ushort f2bf(float x) {
    __hip_bfloat16 h = __float2bfloat16(x);
    return *reinterpret_cast<ushort*>(&h);
}

__device__ __forceinline__ short8 pack8(float4 lo, float4 hi) {
    short8 v;
    v[0] = (short)f2bf(lo.x); v[1] = (short)f2bf(lo.y);
    v[2] = (short)f2bf(lo.z); v[3] = (short)f2bf(lo.w);
    v[4] = (short)f2bf(hi.x); v[5] = (short)f2bf(hi.y);
    v[6] = (short)f2bf(hi.z); v[7] = (short)f2bf(hi.w);
    return v;
}

// 8 edges per wave: each 16-lane group handles TWO edges with all gathers
// issued up front and independent reduce chains interleaved (2x MLP/ILP).
__global__ __launch_bounds__(256) void k_edge_w(
    const float* __restrict__ ufk, const float* __restrict__ mfk,
    const float* __restrict__ ufs, const float* __restrict__ mfs,
    const float* __restrict__ rfeat, const float* __restrict__ proto,
    const float* __restrict__ eta, const int* __restrict__ eu,
    const int* __restrict__ em, const int* __restrict__ kp,
    float* __restrict__ wbuf, float* __restrict__ nrm_u, float* __restrict__ nrm_m)
{
    const int tid = threadIdx.x;
    const int wv = tid >> 6, l = tid & 63;
    const int g16 = l >> 4;          // group within wave
    const int j   = l & 15;          // lane within group
    const int r = blockIdx.y;
    const int rE = r * EDGES;
    const int e0 = (blockIdx.x * 4 + wv) * 8 + g16 * 2;   // EDGES = 3125*32 exact
    const int e1 = e0 + 1;
    const int idx0 = rE + e0, idx1 = rE + e1;
    const int u0 = eu[idx0], m0 = em[idx0];
    const int u1 = eu[idx1], m1 = em[idx1];
    const int kk = kp[0];

    // ---- issue ALL gathers up front (2 edges' chains in flight) ----
    const float4 pu0 = ((const float4*)(ufs + (size_t)(r * NU + u0) * 64))[j];
    const float4 pm0 = ((const float4*)(mfs + (size_t)(r * NM + m0) * 64))[j];
    const float4 pu1 = ((const float4*)(ufs + (size_t)(r * NU + u1) * 64))[j];
    const float4 pm1 = ((const float4*)(mfs + (size_t)(r * NM + m1) * 64))[j];
    const int jc = j & 3;
    const float4 u40 = ((const float4*)(ufk + (size_t)(r * NU + u0) * 16))[jc];
    const float4 m40 = ((const float4*)(mfk + (size_t)(r * NM + m0) * 16))[jc];
    const float4 u41 = ((const float4*)(ufk + (size_t)(r * NU + u1) * 16))[jc];
    const float4 m41 = ((const float4*)(mfk + (size_t)(r * NM + m1) * 16))[jc];

    // ---- sim_all (both edges, interleaved) ----
    float p0 = dot4(pu0, pm0), p1 = dot4(pu1, pm1);
    p0 += __shfl_xor(p0, 1); p1 += __shfl_xor(p1, 1);
    p0 += __shfl_xor(p0, 2); p1 += __shfl_xor(p1, 2);
    float dsim0 = expf(p0 * TAU_INV), dsim1 = expf(p1 * TAU_INV);
    dsim0 += __shfl_xor(dsim0, 4); dsim1 += __shfl_xor(dsim1, 4);
    dsim0 += __shfl_xor(dsim0, 8); dsim1 += __shfl_xor(dsim1, 8);

    // ---- sim_k (both edges) ----
    float su0 = dot4(u40, u40), sm0 = dot4(m40, m40), sd0 = dot4(u40, m40);
    float su1 = dot4(u41, u41), sm1 = dot4(m41, m41), sd1 = dot4(u41, m41);
    su0 += __shfl_xor(su0, 1); su1 += __shfl_xor(su1, 1);
    su0 += __shfl_xor(su0, 2); su1 += __shfl_xor(su1, 2);
    sm0 += __shfl_xor(sm0, 1); sm1 += __shfl_xor(sm1, 1);
    sm0 += __shfl_xor(sm0, 2); sm1 += __shfl_xor(sm1, 2);
    sd0 += __shfl_xor(sd0, 1); sd1 += __shfl_xor(sd1, 1);
    sd0 += __shfl_xor(sd0, 2); sd1 += __shfl_xor(sd1, 2);
    const float nsim0 = expf(sd0 / (fmaxf(sqrtf(su0), 1e-12f) * fmaxf(sqrtf(sm0), 1e-12f)) * TAU_INV);
    const float nsim1 = expf(sd1 / (fmaxf(sqrtf(su1), 1e-12f) * fmaxf(sqrtf(sm1), 1e-12f)) * TAU_INV);

    // ---- anchor (both edges) ----
    const float4* rf40 = (const float4*)(rfeat + (size_t)idx0 * 256);
    const float4* rf41 = (const float4*)(rfeat + (size_t)idx1 * 256);
    const float4* pr4  = (const float4*)proto;
    const int base = (j >> 2) * 16 + (j & 3) * 4;
    float ap0 = 0.f, ap1 = 0.f;
#pragma unroll
    for (int t = 0; t < 4; ++t) {
        const float4 pr = pr4[base + t];
        ap0 += dot4(rf40[base + t], pr);
        ap1 += dot4(rf41[base + t], pr);
    }
    ap0 += __shfl_xor(ap0, 1); ap1 += __shfl_xor(ap1, 1);
    ap0 += __shfl_xor(ap0, 2); ap1 += __shfl_xor(ap1, 2);
    float dan0 = expf(ap0 * TAU_INV), dan1 = expf(ap1 * TAU_INV);
    dan0 += __shfl_xor(dan0, 4); dan1 += __shfl_xor(dan1, 4);
    dan0 += __shfl_xor(dan0, 8); dan1 += __shfl_xor(dan1, 8);
    const int ksrc = (l & 48) | (kk << 2);
    const float na0 = expf(__shfl(ap0, ksrc) * TAU_INV);
    const float na1 = expf(__shfl(ap1, ksrc) * TAU_INV);

    const float gt0 = 1.0f / (1.0f + expf(-eta[idx0]));
    const float gt1 = 1.0f / (1.0f + expf(-eta[idx1]));
    const float w0 = gt0 * (na0 / dan0) + (1.0f - gt0) * (nsim0 / dsim0);
    const float w1 = gt1 * (na1 / dan1) + (1.0f - gt1) * (nsim1 / dsim1);

    if (j == 0) {            // all 16 lanes hold both w's; split the writes
        wbuf[idx0] = w0;
        atomicAdd(&nrm_u[u0], w0);
        atomicAdd(&nrm_m[m0], w0);
    } else if (j == 8) {
        wbuf[idx1] = w1;
        atomicAdd(&nrm_u[u1], w1);
        atomicAdd(&nrm_m[m1], w1);
    }
}

// MFMA msg kernel (R14, unchanged). Per wave: 32 edges. A=[rf|ufk|mfk] bf16 in
// LDS; B_f/B_r register fragments; f32 accum; paired atomic scatter.
__global__ __launch_bounds__(256) void k_edge_msg(
    const float* __restrict__ ufk, const float* __restrict__ mfk,
    const float* __restrict__ rfeat,
    const float* __restrict__ nwf, const float* __restrict__ rwf,
    const float* __restrict__ nwr, const float* __restrict__ rwr,
    const int* __restrict__ eu, const int* __restrict__ em, const int* __restrict__ kp,
    const float* __restrict__ wbuf, const float* __restrict__ nrm_u,
    const float* __restrict__ nrm_m,
    float* __restrict__ upre, float* __restrict__ ipre, float* __restrict__ dist_out)
{
    __shared__ __align__(16) ushort s_a[4][EPW][104];

    const int tid = threadIdx.x;
    const int wv = tid >> 6, l = tid & 63;
    const int o = l & 15, q = l >> 4;
    const int r = blockIdx.y;
    const int kk = kp[0];
    const int rE = r * EDGES;

    short8 Bf[3], Br[3];
    {
        const float* wfp = rwf + (size_t)r * 1024 + o * 64;
        const float* wrp = rwr + (size_t)r * 1024 + o * 64;
        const float* nfp = nwf + r * 256 + o * 16;
        const float* nrp = nwr + r * 256 + o * 16;
#pragma unroll
        for (int sl = 0; sl < 2; ++sl) {
            const int bk = 32 * sl + 8 * q;
            Bf[sl] = pack8(*(const float4*)(wfp + bk), *(const float4*)(wfp + bk + 4));
            Br[sl] = pack8(*(const float4*)(wrp + bk), *(const float4*)(wrp + bk + 4));
        }
        const short8 z8 = {0, 0, 0, 0, 0, 0, 0, 0};
        Bf[2] = (q < 2) ? pack8(*(const float4*)(nfp + 8 * q),
                                *(const float4*)(nfp + 8 * q + 4)) : z8;
        Br[2] = (q >= 2) ? pack8(*(const float4*)(nrp + 8 * (q - 2)),
                                 *(const float4*)(nrp + 8 * (q - 2) + 4)) : z8;
    }

    const int ebase = (blockIdx.x * 4 + wv) * EPW;

    int eu32, em32; float wn32;
    {
        int e2 = ebase + (l & 31); if (e2 >= EDGES) e2 = EDGES - 1;
        eu32 = eu[rE + e2]; em32 = em[rE + e2];
        const float w0 = wbuf[rE + e2];
        wn32 = w0 / sqrtf(nrm_u[eu32] * nrm_m[em32]);
    }
    if (l < 32 && ebase + l < EDGES)
        dist_out[rE + ebase + l] = wn32;

    float4 st[12];
#pragma unroll
    for (int t = 0; t < 12; ++t) {
        const int s = l + 64 * t;
        const int j = s / 24;
        const int p = s % 24;
        int e2 = ebase + j; if (e2 >= EDGES) e2 = EDGES - 1;
        const int uj = __shfl(eu32, j);
        const int mj = __shfl(em32, j);
        const float4* src;
        if (p < 16)      src = (const float4*)(rfeat + ((size_t)(rE + e2) * 4 + kk) * 64) + p;
        else if (p < 20) src = (const float4*)(ufk + (size_t)(r * NU + uj) * 16) + (p - 16);
        else             src = (const float4*)(mfk + (size_t)(r * NM + mj) * 16) + (p - 20);
        st[t] = *src;
    }
    char* abase = (char*)&s_a[wv][0][0];
#pragma unroll
    for (int t = 0; t < 12; ++t) {
        const int s = l + 64 * t;
        const int j = s / 24;
        const int p = s % 24;
        uint2 wds;
        wds.x = (uint)f2bf(st[t].x) | ((uint)f2bf(st[t].y) << 16);
        wds.y = (uint)f2bf(st[t].z) | ((uint)f2bf(st[t].w) << 16);
        *(uint2*)(abase + j * 208 + p * 8) = wds;
    }

#pragma unroll
    for (int g = 0; g < 2; ++g) {
        f32x4 accm = {0.f, 0.f, 0.f, 0.f};
        f32x4 accu = {0.f, 0.f, 0.f, 0.f};
        const int row = g * 16 + o;
#pragma unroll
        for (int sl = 0; sl < 3; ++sl) {
            const short8 a = *(const short8*)(abase + row * 208 + (sl * 32 + 8 * q) * 2);
            accm = __builtin_amdgcn_mfma_f32_16x16x32_bf16(a, Bf[sl], accm, 0, 0, 0);
            accu = __builtin_amdgcn_mfma_f32_16x16x32_bf16(a, Br[sl], accu, 0, 0, 0);
        }
#pragma unroll
        for (int i = 0; i < 4; ++i) {
            const int j = g * 16 + q * 4 + i;
            const float wnj = __shfl(wn32, j);
            const int   uj  = __shfl(eu32, j);
            const int   mj  = __shfl(em32, j);
            const bool  livej = (ebase + j) < EDGES;
            const float vm = accm[i] * wnj;
            const float vu = accu[i] * wnj;
            if (livej) {
                atomicAdd(&ipre[(size_t)mj * 16 + o], vm);
                atomicAdd(&upre[(size_t)uj * 16 + o], vu);
            }
        }
    }
}

// Fused leaky-relu + (N,16) x (16,64) FC for both tables. (unchanged)
__global__ __launch_bounds__(256) void k_fc(
    const float* __restrict__ upre, const float* __restrict__ ipre,
    const float* __restrict__ uw, const float* __restrict__ ub,
    const float* __restrict__ iw, const float* __restrict__ ib,
    float* __restrict__ out_u, float* __restrict__ out_i)
{
    const int tid = threadIdx.x;
    const int n = blockIdx.x * 4 + (tid >> 6);
    if (n >= NU + NM) return;
    const int o = tid & 63;
    const float* pre; const float* W; const float* B; float* dst;
    if (n < NU) { pre = upre + (size_t)n * 16; W = uw; B = ub; dst = out_u + (size_t)n * 64; }
    else { int n2 = n - NU; pre = ipre + (size_t)n2 * 16; W = iw; B = ib; dst = out_i + (size_t)n2 * 64; }
    float acc = B[o];
#pragma unroll
    for (int d = 0; d < 16; d++) {
        float x = pre[d];
        x = x >= 0.f ? x : 0.1f * x;
        acc += x * W[o * 16 + d];
    }
    dst[o] = acc;
}

extern "C" void kernel_launch(void* const* d_in, const int* in_sizes, int n_in,
                              void* d_out, int out_size, void* d_ws, size_t ws_size,
                              hipStream_t stream) {
    const float* ufk  = (const float*)d_in[0];
    const float* mfk  = (const float*)d_in[1];
    const float* ufs  = (const float*)d_in[2];
    const float* mfs  = (const float*)d_in[3];
    const float* rfe  = (const float*)d_in[4];
    const float* pro  = (const float*)d_in[5];
    const float* eta  = (const float*)d_in[6];
    const float* nwf  = (const float*)d_in[7];
    const float* rwf  = (const float*)d_in[8];
    const float* nwr  = (const float*)d_in[9];
    const float* rwr  = (const float*)d_in[10];
    const float* uw   = (const float*)d_in[11];
    const float* ub   = (const float*)d_in[12];
    const float* iw   = (const float*)d_in[13];
    const float* ib   = (const float*)d_in[14];
    const int*   eu   = (const int*)d_in[15];
    const int*   em   = (const int*)d_in[16];
    const int*   kp   = (const int*)d_in[17];

    float* out    = (float*)d_out;
    float* out_u  = out;                         // NU*64
    float* out_i  = out + (size_t)NU * 64;       // NM*64
    float* out_d  = out_i + (size_t)NM * 64;     // R*E

    float* ws    = (float*)d_ws;
    float* nrm_u = ws;                           // NU
    float* nrm_m = nrm_u + NU;                   // NM
    float* upre  = nrm_m + NM;                   // NU*16
    float* ipre  = upre + (size_t)NU * 16;       // NM*16
    float* wbuf  = ipre + (size_t)NM * 16;       // R*E

    const size_t zeroN = (size_t)NU + NM + (size_t)NU * 16 + (size_t)NM * 16;
    hipMemsetAsync(d_ws, 0, zeroN * sizeof(float), stream);

    dim3 gW((EDGES + 31) / 32, R_);
    k_edge_w<<<gW, 256, 0, stream>>>(ufk, mfk, ufs, mfs, rfe, pro, eta, eu, em, kp,
                                     wbuf, nrm_u, nrm_m);
    dim3 gM((EDGES + 4 * EPW - 1) / (4 * EPW), R_);
    k_edge_msg<<<gM, 256, 0, stream>>>(ufk, mfk, rfe, nwf, rwf, nwr, rwr, eu, em, kp,
                                       wbuf, nrm_u, nrm_m, upre, ipre, out_d);
    k_fc<<<((NU + NM) + 3) / 4, 256, 0, stream>>>(upre, ipre, uw, ub, iw, ib, out_u, out_i);
}

// Round 17
// 258.363 us; speedup vs baseline: 1.5128x; 1.0550x over previous
//
#include <hip/hip_runtime.h>
#include <hip/hip_bf16.h>

#define TAU_INV 2.0f
#define R_ 5
#define NU 50000
#define NM 20000
#define EDGES 100000
#define OUT_ 64
#define EPW 32

typedef __attribute__((ext_vector_type(8))) short short8;  // 8 bf16
typedef __attribute__((ext_vector_type(4))) float f32x4;

__device__ __forceinline__ float dot4(float4 a, float4 b) {
    return a.x * b.x + a.y * b.y + a.z * b.z + a.w * b.w;
}
__device__ __forceinline__ ushort f2bf(float x) {
    __hip_bfloat16 h = __float2bfloat16(x);
    return *reinterpret_cast<ushort*>(&h);
}
__device__ __forceinline__ uint pk2(float a, float b) {
    return (uint)f2bf(a) | ((uint)f2bf(b) << 16);
}
__device__ __forceinline__ short8 pack8(float4 lo, float4 hi) {
    short8 v;
    v[0] = (short)f2bf(lo.x); v[1] = (short)f2bf(lo.y);
    v[2] = (short)f2bf(lo.z); v[3] = (short)f2bf(lo.w);
    v[4] = (short)f2bf(hi.x); v[5] = (short)f2bf(hi.y);
    v[6] = (short)f2bf(hi.z); v[7] = (short)f2bf(hi.w);
    return v;
}

// R12-form gating kernel: 4 edges/wave, 16 lanes/edge. SPILL: lanes holding the
// rf k-row additionally store it bf16-packed (128B/edge) for the msg kernel.
template<bool SPILL>
__global__ __launch_bounds__(256) void k_edge_w(
    const float* __restrict__ ufk, const float* __restrict__ mfk,
    const float* __restrict__ ufs, const float* __restrict__ mfs,
    const float* __restrict__ rfeat, const float* __restrict__ proto,
    const float* __restrict__ eta, const int* __restrict__ eu,
    const int* __restrict__ em, const int* __restrict__ kp,
    float* __restrict__ wbuf, float* __restrict__ nrm_u, float* __restrict__ nrm_m,
    ushort* __restrict__ msgA)
{
    const int tid = threadIdx.x;
    const int wv = tid >> 6, l = tid & 63;
    const int g16 = l >> 4;
    const int j   = l & 15;
    const int r = blockIdx.y;
    const int e = (blockIdx.x * 4 + wv) * 4 + g16;   // 6250*16 = 100000 exact
    const int idx = r * EDGES + e;
    const int u = eu[idx], m = em[idx];
    const int kk = kp[0];

    const float4 pu = ((const float4*)(ufs + (size_t)(r * NU + u) * 64))[j];
    const float4 pm = ((const float4*)(mfs + (size_t)(r * NM + m) * 64))[j];
    float p = dot4(pu, pm);
    p += __shfl_xor(p, 1); p += __shfl_xor(p, 2);
    const float es = expf(p * TAU_INV);
    float dsim = es;
    dsim += __shfl_xor(dsim, 4); dsim += __shfl_xor(dsim, 8);

    const int jc = j & 3;
    const float4 u4 = ((const float4*)(ufk + (size_t)(r * NU + u) * 16))[jc];
    const float4 m4 = ((const float4*)(mfk + (size_t)(r * NM + m) * 16))[jc];
    float su = dot4(u4, u4), sm = dot4(m4, m4), sd = dot4(u4, m4);
    su += __shfl_xor(su, 1); su += __shfl_xor(su, 2);
    sm += __shfl_xor(sm, 1); sm += __shfl_xor(sm, 2);
    sd += __shfl_xor(sd, 1); sd += __shfl_xor(sd, 2);
    const float nsim = expf(sd / (fmaxf(sqrtf(su), 1e-12f) * fmaxf(sqrtf(sm), 1e-12f)) * TAU_INV);

    const float4* rf4 = (const float4*)(rfeat + (size_t)idx * 256);
    const float4* pr4 = (const float4*)proto;
    const int base = (j >> 2) * 16 + (j & 3) * 4;
    const float4 rr0 = rf4[base + 0], rr1 = rf4[base + 1];
    const float4 rr2 = rf4[base + 2], rr3 = rf4[base + 3];
    float ap = dot4(rr0, pr4[base + 0]) + dot4(rr1, pr4[base + 1])
             + dot4(rr2, pr4[base + 2]) + dot4(rr3, pr4[base + 3]);
    ap += __shfl_xor(ap, 1); ap += __shfl_xor(ap, 2);
    const float ea = expf(ap * TAU_INV);
    float dan = ea;
    dan += __shfl_xor(dan, 4); dan += __shfl_xor(dan, 8);
    const float adk = __shfl(ap, (l & 48) | (kk << 2));
    const float na = expf(adk * TAU_INV);

    const float gt = 1.0f / (1.0f + expf(-eta[idx]));
    const float w = gt * (na / dan) + (1.0f - gt) * (nsim / dsim);

    if (j == 0) {
        wbuf[idx] = w;
        atomicAdd(&nrm_u[u], w);
        atomicAdd(&nrm_m[m], w);
    }

    if (SPILL && (j >> 2) == kk) {
        // this lane's rr0..rr3 = k-row floats [(j&3)*16, +16): spill bf16
        uint4 w0, w1;
        w0.x = pk2(rr0.x, rr0.y); w0.y = pk2(rr0.z, rr0.w);
        w0.z = pk2(rr1.x, rr1.y); w0.w = pk2(rr1.z, rr1.w);
        w1.x = pk2(rr2.x, rr2.y); w1.y = pk2(rr2.z, rr2.w);
        w1.z = pk2(rr3.x, rr3.y); w1.w = pk2(rr3.z, rr3.w);
        uint4* dst = (uint4*)(msgA + (size_t)idx * 64 + (j & 3) * 16);
        dst[0] = w0; dst[1] = w1;
    }
}

// LDS-free MFMA msg kernel: A slices 0-1 load coalesced from bf16 msgA
// (row-slice = one 64B line); slice 2 gathers ufk/mfk f32 rows and packs.
__global__ __launch_bounds__(256) void k_msg_direct(
    const float* __restrict__ ufk, const float* __restrict__ mfk,
    const ushort* __restrict__ msgA,
    const float* __restrict__ nwf, const float* __restrict__ rwf,
    const float* __restrict__ nwr, const float* __restrict__ rwr,
    const int* __restrict__ eu, const int* __restrict__ em,
    const float* __restrict__ wbuf, const float* __restrict__ nrm_u,
    const float* __restrict__ nrm_m,
    float* __restrict__ upre, float* __restrict__ ipre, float* __restrict__ dist_out)
{
    const int tid = threadIdx.x;
    const int wv = tid >> 6, l = tid & 63;
    const int o = l & 15, q = l >> 4;
    const int r = blockIdx.y;
    const int rE = r * EDGES;

    short8 Bf[3], Br[3];
    {
        const float* wfp = rwf + (size_t)r * 1024 + o * 64;
        const float* wrp = rwr + (size_t)r * 1024 + o * 64;
        const float* nfp = nwf + r * 256 + o * 16;
        const float* nrp = nwr + r * 256 + o * 16;
#pragma unroll
        for (int sl = 0; sl < 2; ++sl) {
            const int bk = 32 * sl + 8 * q;
            Bf[sl] = pack8(*(const float4*)(wfp + bk), *(const float4*)(wfp + bk + 4));
            Br[sl] = pack8(*(const float4*)(wrp + bk), *(const float4*)(wrp + bk + 4));
        }
        const short8 z8 = {0, 0, 0, 0, 0, 0, 0, 0};
        Bf[2] = (q < 2) ? pack8(*(const float4*)(nfp + 8 * q),
                                *(const float4*)(nfp + 8 * q + 4)) : z8;
        Br[2] = (q >= 2) ? pack8(*(const float4*)(nrp + 8 * (q - 2)),
                                 *(const float4*)(nrp + 8 * (q - 2) + 4)) : z8;
    }

    const int ebase = (blockIdx.x * 4 + wv) * EPW;

    int eu32, em32; float wn32;
    {
        int e2 = ebase + (l & 31); if (e2 >= EDGES) e2 = EDGES - 1;
        eu32 = eu[rE + e2]; em32 = em[rE + e2];
        const float w0 = wbuf[rE + e2];
        wn32 = w0 / sqrtf(nrm_u[eu32] * nrm_m[em32]);
    }
    if (l < 32 && ebase + l < EDGES)
        dist_out[rE + ebase + l] = wn32;

#pragma unroll
    for (int g = 0; g < 2; ++g) {
        const int erow = g * 16 + o;                 // edge slot 0..31
        int e2 = ebase + erow; if (e2 >= EDGES) e2 = EDGES - 1;
        const int u_r = __shfl(eu32, erow);          // full convergence
        const int m_r = __shfl(em32, erow);

        // A slices 0,1: direct bf16 loads (coalesced: 4 lanes per 64B line)
        const char* arow = (const char*)(msgA + (size_t)(rE + e2) * 64);
        const short8 a0 = *(const short8*)(arow + 0 * 64 + q * 16);
        const short8 a1 = *(const short8*)(arow + 1 * 64 + q * 16);
        // A slice 2: gather node row (f32) + pack
        const float* nb = (q < 2) ? (ufk + (size_t)(r * NU + u_r) * 16 + (q & 1) * 8)
                                  : (mfk + (size_t)(r * NM + m_r) * 16 + (q & 1) * 8);
        const short8 a2 = pack8(((const float4*)nb)[0], ((const float4*)nb)[1]);

        f32x4 accm = {0.f, 0.f, 0.f, 0.f};
        f32x4 accu = {0.f, 0.f, 0.f, 0.f};
        accm = __builtin_amdgcn_mfma_f32_16x16x32_bf16(a0, Bf[0], accm, 0, 0, 0);
        accu = __builtin_amdgcn_mfma_f32_16x16x32_bf16(a0, Br[0], accu, 0, 0, 0);
        accm = __builtin_amdgcn_mfma_f32_16x16x32_bf16(a1, Bf[1], accm, 0, 0, 0);
        accu = __builtin_amdgcn_mfma_f32_16x16x32_bf16(a1, Br[1], accu, 0, 0, 0);
        accm = __builtin_amdgcn_mfma_f32_16x16x32_bf16(a2, Bf[2], accm, 0, 0, 0);
        accu = __builtin_amdgcn_mfma_f32_16x16x32_bf16(a2, Br[2], accu, 0, 0, 0);

#pragma unroll
        for (int i = 0; i < 4; ++i) {
            const int j = g * 16 + q * 4 + i;
            const float wnj = __shfl(wn32, j);
            const int   uj  = __shfl(eu32, j);
            const int   mj  = __shfl(em32, j);
            const bool  livej = (ebase + j) < EDGES;
            const float vm = accm[i] * wnj;
            const float vu = accu[i] * wnj;
            if (livej) {
                atomicAdd(&ipre[(size_t)mj * 16 + o], vm);
                atomicAdd(&upre[(size_t)uj * 16 + o], vu);
            }
        }
    }
}

// R14 LDS-staging msg kernel — fallback when ws is too small for msgA.
__global__ __launch_bounds__(256) void k_msg_lds(
    const float* __restrict__ ufk, const float* __restrict__ mfk,
    const float* __restrict__ rfeat,
    const float* __restrict__ nwf, const float* __restrict__ rwf,
    const float* __restrict__ nwr, const float* __restrict__ rwr,
    const int* __restrict__ eu, const int* __restrict__ em, const int* __restrict__ kp,
    const float* __restrict__ wbuf, const float* __restrict__ nrm_u,
    const float* __restrict__ nrm_m,
    float* __restrict__ upre, float* __restrict__ ipre, float* __restrict__ dist_out)
{
    __shared__ __align__(16) ushort s_a[4][EPW][104];
    const int tid = threadIdx.x;
    const int wv = tid >> 6, l = tid & 63;
    const int o = l & 15, q = l >> 4;
    const int r = blockIdx.y;
    const int kk = kp[0];
    const int rE = r * EDGES;

    short8 Bf[3], Br[3];
    {
        const float* wfp = rwf + (size_t)r * 1024 + o * 64;
        const float* wrp = rwr + (size_t)r * 1024 + o * 64;
        const float* nfp = nwf + r * 256 + o * 16;
        const float* nrp = nwr + r * 256 + o * 16;
#pragma unroll
        for (int sl = 0; sl < 2; ++sl) {
            const int bk = 32 * sl + 8 * q;
            Bf[sl] = pack8(*(const float4*)(wfp + bk), *(const float4*)(wfp + bk + 4));
            Br[sl] = pack8(*(const float4*)(wrp + bk), *(const float4*)(wrp + bk + 4));
        }
        const short8 z8 = {0, 0, 0, 0, 0, 0, 0, 0};
        Bf[2] = (q < 2) ? pack8(*(const float4*)(nfp + 8 * q),
                                *(const float4*)(nfp + 8 * q + 4)) : z8;
        Br[2] = (q >= 2) ? pack8(*(const float4*)(nrp + 8 * (q - 2)),
                                 *(const float4*)(nrp + 8 * (q - 2) + 4)) : z8;
    }

    const int ebase = (blockIdx.x * 4 + wv) * EPW;
    int eu32, em32; float wn32;
    {
        int e2 = ebase + (l & 31); if (e2 >= EDGES) e2 = EDGES - 1;
        eu32 = eu[rE + e2]; em32 = em[rE + e2];
        const float w0 = wbuf[rE + e2];
        wn32 = w0 / sqrtf(nrm_u[eu32] * nrm_m[em32]);
    }
    if (l < 32 && ebase + l < EDGES)
        dist_out[rE + ebase + l] = wn32;

    float4 st[12];
#pragma unroll
    for (int t = 0; t < 12; ++t) {
        const int s = l + 64 * t;
        const int j = s / 24, p = s % 24;
        int e2 = ebase + j; if (e2 >= EDGES) e2 = EDGES - 1;
        const int uj = __shfl(eu32, j);
        const int mj = __shfl(em32, j);
        const float4* src;
        if (p < 16)      src = (const float4*)(rfeat + ((size_t)(rE + e2) * 4 + kk) * 64) + p;
        else if (p < 20) src = (const float4*)(ufk + (size_t)(r * NU + uj) * 16) + (p - 16);
        else             src = (const float4*)(mfk + (size_t)(r * NM + mj) * 16) + (p - 20);
        st[t] = *src;
    }
    char* abase = (char*)&s_a[wv][0][0];
#pragma unroll
    for (int t = 0; t < 12; ++t) {
        const int s = l + 64 * t;
        const int j = s / 24, p = s % 24;
        uint2 wds;
        wds.x = pk2(st[t].x, st[t].y);
        wds.y = pk2(st[t].z, st[t].w);
        *(uint2*)(abase + j * 208 + p * 8) = wds;
    }

#pragma unroll
    for (int g = 0; g < 2; ++g) {
        f32x4 accm = {0.f, 0.f, 0.f, 0.f};
        f32x4 accu = {0.f, 0.f, 0.f, 0.f};
        const int row = g * 16 + o;
#pragma unroll
        for (int sl = 0; sl < 3; ++sl) {
            const short8 a = *(const short8*)(abase + row * 208 + (sl * 32 + 8 * q) * 2);
            accm = __builtin_amdgcn_mfma_f32_16x16x32_bf16(a, Bf[sl], accm, 0, 0, 0);
            accu = __builtin_amdgcn_mfma_f32_16x16x32_bf16(a, Br[sl], accu, 0, 0, 0);
        }
#pragma unroll
        for (int i = 0; i < 4; ++i) {
            const int j = g * 16 + q * 4 + i;
            const float wnj = __shfl(wn32, j);
            const int   uj  = __shfl(eu32, j);
            const int   mj  = __shfl(em32, j);
            const bool  livej = (ebase + j) < EDGES;
            const float vm = accm[i] * wnj;
            const float vu = accu[i] * wnj;
            if (livej) {
                atomicAdd(&ipre[(size_t)mj * 16 + o], vm);
                atomicAdd(&upre[(size_t)uj * 16 + o], vu);
            }
        }
    }
}

// Fused leaky-relu + (N,16) x (16,64) FC for both tables.
__global__ __launch_bounds__(256) void k_fc(
    const float* __restrict__ upre, const float* __restrict__ ipre,
    const float* __restrict__ uw, const float* __restrict__ ub,
    const float* __restrict__ iw, const float* __restrict__ ib,
    float* __restrict__ out_u, float* __restrict__ out_i)
{
    const int tid = threadIdx.x;
    const int n = blockIdx.x * 4 + (tid >> 6);
    if (n >= NU + NM) return;
    const int o = tid & 63;
    const float* pre; const float* W; const float* B; float* dst;
    if (n < NU) { pre = upre + (size_t)n * 16; W = uw; B = ub; dst = out_u + (size_t)n * 64; }
    else { int n2 = n - NU; pre = ipre + (size_t)n2 * 16; W = iw; B = ib; dst = out_i + (size_t)n2 * 64; }
    float acc = B[o];
#pragma unroll
    for (int d = 0; d < 16; d++) {
        float x = pre[d];
        x = x >= 0.f ? x : 0.1f * x;
        acc += x * W[o * 16 + d];
    }
    dst[o] = acc;
}

extern "C" void kernel_launch(void* const* d_in, const int* in_sizes, int n_in,
                              void* d_out, int out_size, void* d_ws, size_t ws_size,
                              hipStream_t stream) {
    const float* ufk  = (const float*)d_in[0];
    const float* mfk  = (const float*)d_in[1];
    const float* ufs  = (const float*)d_in[2];
    const float* mfs  = (const float*)d_in[3];
    const float* rfe  = (const float*)d_in[4];
    const float* pro  = (const float*)d_in[5];
    const float* eta  = (const float*)d_in[6];
    const float* nwf  = (const float*)d_in[7];
    const float* rwf  = (const float*)d_in[8];
    const float* nwr  = (const float*)d_in[9];
    const float* rwr  = (const float*)d_in[10];
    const float* uw   = (const float*)d_in[11];
    const float* ub   = (const float*)d_in[12];
    const float* iw   = (const float*)d_in[13];
    const float* ib   = (const float*)d_in[14];
    const int*   eu   = (const int*)d_in[15];
    const int*   em   = (const int*)d_in[16];
    const int*   kp   = (const int*)d_in[17];

    float* out    = (float*)d_out;
    float* out_u  = out;                         // NU*64
    float* out_i  = out + (size_t)NU * 64;       // NM*64
    float* out_d  = out_i + (size_t)NM * 64;     // R*E

    float* ws    = (float*)d_ws;
    float* nrm_u = ws;                           // NU
    float* nrm_m = nrm_u + NU;                   // NM
    float* upre  = nrm_m + NM;                   // NU*16
    float* ipre  = upre + (size_t)NU * 16;       // NM*16
    float* wbuf  = ipre + (size_t)NM * 16;       // R*E
    ushort* msgA = (ushort*)(wbuf + (size_t)R_ * EDGES);  // R*E*64 bf16 = 64 MB

    const size_t baseFloats = (size_t)NU + NM + (size_t)NU * 16 + (size_t)NM * 16
                            + (size_t)R_ * EDGES;
    const size_t need = baseFloats * 4 + (size_t)R_ * EDGES * 64 * 2;
    const bool spill = (ws_size >= need);

    const size_t zeroN = (size_t)NU + NM + (size_t)NU * 16 + (size_t)NM * 16;
    hipMemsetAsync(d_ws, 0, zeroN * sizeof(float), stream);

    dim3 gW((EDGES + 15) / 16, R_);
    dim3 gM((EDGES + 4 * EPW - 1) / (4 * EPW), R_);
    if (spill) {
        k_edge_w<true><<<gW, 256, 0, stream>>>(ufk, mfk, ufs, mfs, rfe, pro, eta,
                                               eu, em, kp, wbuf, nrm_u, nrm_m, msgA);
        k_msg_direct<<<gM, 256, 0, stream>>>(ufk, mfk, msgA, nwf, rwf, nwr, rwr,
                                             eu, em, wbuf, nrm_u, nrm_m,
                                             upre, ipre, out_d);
    } else {
        k_edge_w<false><<<gW, 256, 0, stream>>>(ufk, mfk, ufs, mfs, rfe, pro, eta,
                                                eu, em, kp, wbuf, nrm_u, nrm_m, msgA);
        k_msg_lds<<<gM, 256, 0, stream>>>(ufk, mfk, rfe, nwf, rwf, nwr, rwr,
                                          eu, em, kp, wbuf, nrm_u, nrm_m,
                                          upre, ipre, out_d);
    }
    k_fc<<<((NU + NM) + 3) / 4, 256, 0, stream>>>(upre, ipre, uw, ub, iw, ib, out_u, out_i);
}

// Round 18
// 245.210 us; speedup vs baseline: 1.5939x; 1.0536x over previous
//
#include <hip/hip_runtime.h>
#include <hip/hip_bf16.h>

#define TAU_INV 2.0f
#define R_ 5
#define NU 50000
#define NM 20000
#define EDGES 100000
#define OUT_ 64

typedef __attribute__((ext_vector_type(8))) short short8;  // 8 bf16
typedef __attribute__((ext_vector_type(4))) float f32x4;

__device__ __forceinline__ float dot4(float4 a, float4 b) {
    return a.x * b.x + a.y * b.y + a.z * b.z + a.w * b.w;
}
__device__ __forceinline__ ushort f2bf(float x) {
    __hip_bfloat16 h = __float2bfloat16(x);
    return *reinterpret_cast<ushort*>(&h);
}
__device__ __forceinline__ uint pk2(float a, float b) {
    return (uint)f2bf(a) | ((uint)f2bf(b) << 16);
}
__device__ __forceinline__ float bf2f(ushort u) {
    uint v = ((uint)u) << 16;
    return *reinterpret_cast<float*>(&v);
}
__device__ __forceinline__ short8 pack8(float4 lo, float4 hi) {
    short8 v;
    v[0] = (short)f2bf(lo.x); v[1] = (short)f2bf(lo.y);
    v[2] = (short)f2bf(lo.z); v[3] = (short)f2bf(lo.w);
    v[4] = (short)f2bf(hi.x); v[5] = (short)f2bf(hi.y);
    v[6] = (short)f2bf(hi.z); v[7] = (short)f2bf(hi.w);
    return v;
}

// Gating (R12-form) + BLOCK-level MFMA message fusion:
// phase 1: per-edge gating weight w (16 lanes/edge, 4 edges/wave, 16 edges/block).
// phase 2: lanes already holding rf-k-row / ufk / mfk chunks stage them bf16 into
// a 16x[104] LDS A-tile (R14's proven layout); one barrier; wave 0 runs the 6
// proven MFMAs (A shared between fwd/rev B) and streams pre-wn messages to msgP.
// This deletes the entire second edge pass (rfeat re-read + node gathers).
__global__ __launch_bounds__(256) void k_edge_w(
    const float* __restrict__ ufk, const float* __restrict__ mfk,
    const float* __restrict__ ufs, const float* __restrict__ mfs,
    const float* __restrict__ rfeat, const float* __restrict__ proto,
    const float* __restrict__ eta, const int* __restrict__ eu,
    const int* __restrict__ em, const int* __restrict__ kp,
    const float* __restrict__ nwf, const float* __restrict__ rwf,
    const float* __restrict__ nwr, const float* __restrict__ rwr,
    float* __restrict__ wbuf, float* __restrict__ nrm_u, float* __restrict__ nrm_m,
    uint* __restrict__ msgP)
{
    __shared__ __align__(16) ushort s_a[16][104];   // 3.3 KB A-tile: [edge][k]

    const int tid = threadIdx.x;
    const int wv = tid >> 6, l = tid & 63;
    const int g16 = l >> 4;
    const int j   = l & 15;
    const int r = blockIdx.y;
    const int rE = r * EDGES;
    const int e = (blockIdx.x * 4 + wv) * 4 + g16;   // 6250*16 = 100000 exact
    const int idx = rE + e;
    const int u = eu[idx], m = em[idx];
    const int kk = kp[0];

    // ======== phase 1: gating weight (R12 math, unchanged) ========
    const float4 pu = ((const float4*)(ufs + (size_t)(r * NU + u) * 64))[j];
    const float4 pm = ((const float4*)(mfs + (size_t)(r * NM + m) * 64))[j];
    float p = dot4(pu, pm);
    p += __shfl_xor(p, 1); p += __shfl_xor(p, 2);
    const float es = expf(p * TAU_INV);
    float dsim = es;
    dsim += __shfl_xor(dsim, 4); dsim += __shfl_xor(dsim, 8);

    const int jc = j & 3;
    const float4 u4 = ((const float4*)(ufk + (size_t)(r * NU + u) * 16))[jc];
    const float4 m4 = ((const float4*)(mfk + (size_t)(r * NM + m) * 16))[jc];
    float su = dot4(u4, u4), sm = dot4(m4, m4), sd = dot4(u4, m4);
    su += __shfl_xor(su, 1); su += __shfl_xor(su, 2);
    sm += __shfl_xor(sm, 1); sm += __shfl_xor(sm, 2);
    sd += __shfl_xor(sd, 1); sd += __shfl_xor(sd, 2);
    const float nsim = expf(sd / (fmaxf(sqrtf(su), 1e-12f) * fmaxf(sqrtf(sm), 1e-12f)) * TAU_INV);

    const float4* rf4 = (const float4*)(rfeat + (size_t)idx * 256);
    const float4* pr4 = (const float4*)proto;
    const int base = (j >> 2) * 16 + (j & 3) * 4;
    const float4 rr0 = rf4[base + 0], rr1 = rf4[base + 1];
    const float4 rr2 = rf4[base + 2], rr3 = rf4[base + 3];
    float ap = dot4(rr0, pr4[base + 0]) + dot4(rr1, pr4[base + 1])
             + dot4(rr2, pr4[base + 2]) + dot4(rr3, pr4[base + 3]);
    ap += __shfl_xor(ap, 1); ap += __shfl_xor(ap, 2);
    const float ea = expf(ap * TAU_INV);
    float dan = ea;
    dan += __shfl_xor(dan, 4); dan += __shfl_xor(dan, 8);
    const float adk = __shfl(ap, (l & 48) | (kk << 2));
    const float na = expf(adk * TAU_INV);

    const float gt = 1.0f / (1.0f + expf(-eta[idx]));
    const float w = gt * (na / dan) + (1.0f - gt) * (nsim / dsim);

    if (j == 0) {
        wbuf[idx] = w;
        atomicAdd(&nrm_u[u], w);
        atomicAdd(&nrm_m[m], w);
    }

    // ======== phase 2a: stage A rows (bf16) from registers ========
    const int E = wv * 4 + g16;              // block edge slot 0..15
    char* arow = (char*)&s_a[E][0];
    if ((j >> 2) == kk) {                    // this lane's rr0..3 = k-row chunk c
        const int c = j & 3;                 // k-range [c*16, c*16+16)
        uint4 w0, w1;
        w0.x = pk2(rr0.x, rr0.y); w0.y = pk2(rr0.z, rr0.w);
        w0.z = pk2(rr1.x, rr1.y); w0.w = pk2(rr1.z, rr1.w);
        w1.x = pk2(rr2.x, rr2.y); w1.y = pk2(rr2.z, rr2.w);
        w1.z = pk2(rr3.x, rr3.y); w1.w = pk2(rr3.z, rr3.w);
        *(uint4*)(arow + c * 32)      = w0;
        *(uint4*)(arow + c * 32 + 16) = w1;
    }
    if (j < 4) {                             // ufk row chunk jc=j -> k 64..79
        uint2 wd; wd.x = pk2(u4.x, u4.y); wd.y = pk2(u4.z, u4.w);
        *(uint2*)(arow + 128 + j * 8) = wd;
    } else if (j < 8) {                      // mfk row chunk jc=j-4 -> k 80..95
        uint2 wd; wd.x = pk2(m4.x, m4.y); wd.y = pk2(m4.z, m4.w);
        *(uint2*)(arow + 160 + (j - 4) * 8) = wd;
    }

    // ======== phase 2b: wave 0 loads B-frags BEFORE the barrier ========
    short8 Bf[3], Br[3];
    if (wv == 0) {
        const int o = l & 15, q = l >> 4;
        const float* wfp = rwf + (size_t)r * 1024 + o * 64;
        const float* wrp = rwr + (size_t)r * 1024 + o * 64;
        const float* nfp = nwf + r * 256 + o * 16;
        const float* nrp = nwr + r * 256 + o * 16;
#pragma unroll
        for (int sl = 0; sl < 2; ++sl) {
            const int bk = 32 * sl + 8 * q;
            Bf[sl] = pack8(*(const float4*)(wfp + bk), *(const float4*)(wfp + bk + 4));
            Br[sl] = pack8(*(const float4*)(wrp + bk), *(const float4*)(wrp + bk + 4));
        }
        const short8 z8 = {0, 0, 0, 0, 0, 0, 0, 0};
        Bf[2] = (q < 2) ? pack8(*(const float4*)(nfp + 8 * q),
                                *(const float4*)(nfp + 8 * q + 4)) : z8;
        Br[2] = (q >= 2) ? pack8(*(const float4*)(nrp + 8 * (q - 2)),
                                 *(const float4*)(nrp + 8 * (q - 2) + 4)) : z8;
    }

    __syncthreads();

    // ======== phase 2c: wave 0 MFMA + msgP stream-out (pre-wn) ========
    if (wv == 0) {
        const int o = l & 15, q = l >> 4;
        f32x4 accm = {0.f, 0.f, 0.f, 0.f};
        f32x4 accu = {0.f, 0.f, 0.f, 0.f};
        const int row = l & 15;              // A row = block edge slot
#pragma unroll
        for (int sl = 0; sl < 3; ++sl) {
            const short8 a = *(const short8*)((const char*)&s_a[row][0] + (sl * 32 + 8 * q) * 2);
            accm = __builtin_amdgcn_mfma_f32_16x16x32_bf16(a, Bf[sl], accm, 0, 0, 0);
            accu = __builtin_amdgcn_mfma_f32_16x16x32_bf16(a, Br[sl], accu, 0, 0, 0);
        }
        const int eb = blockIdx.x * 16;      // block edge base
#pragma unroll
        for (int i = 0; i < 4; ++i) {
            const int ej = q * 4 + i;        // D row = edge slot (m89 layout)
            msgP[((size_t)rE + eb + ej) * 16 + o] = pk2(accm[i], accu[i]);
        }
    }
}

// R15-proven scatter: per edge read 64B packed pre-wn message, apply wn,
// two atomic RMWs. 8 edges per wave. (verbatim from round 15, 36 us measured)
__global__ __launch_bounds__(256) void k_scatter(
    const int* __restrict__ eu, const int* __restrict__ em,
    const float* __restrict__ wbuf, const float* __restrict__ nrm_u,
    const float* __restrict__ nrm_m, const uint* __restrict__ msg,
    float* __restrict__ upre, float* __restrict__ ipre, float* __restrict__ dist_out)
{
    const int tid = threadIdx.x;
    const int wv = tid >> 6, l = tid & 63;
    const int o = l & 15;
    const int r = blockIdx.y;
    const int rE = r * EDGES;
    const int ebase = (blockIdx.x * 4 + wv) * 8;   // EDGES = 3125*32 exact

    float wnsave = 0.f;
#pragma unroll
    for (int j = 0; j < 8; j += 2) {
        const int e0 = ebase + j, e1 = e0 + 1;
        const int u0 = eu[rE + e0], m0 = em[rE + e0];
        const int u1 = eu[rE + e1], m1 = em[rE + e1];
        const float wn0 = wbuf[rE + e0] / sqrtf(nrm_u[u0] * nrm_m[m0]);
        const float wn1 = wbuf[rE + e1] / sqrtf(nrm_u[u1] * nrm_m[m1]);
        if (l == j)     wnsave = wn0;
        if (l == j + 1) wnsave = wn1;

        const int  half = l >> 5;
        const int  eh   = half ? e1 : e0;
        const uint pk   = msg[(size_t)(rE + eh) * 16 + o];
        const float wnh = half ? wn1 : wn0;
        const bool up   = (l & 31) >= 16;
        const float val = bf2f(up ? (ushort)(pk >> 16) : (ushort)(pk & 0xffff)) * wnh;
        const int  uh   = half ? u1 : u0;
        const int  mh   = half ? m1 : m0;
        float* basep = up ? &upre[(size_t)uh * 16 + o] : &ipre[(size_t)mh * 16 + o];
        atomicAdd(basep, val);
    }
    if (l < 8)
        dist_out[rE + ebase + l] = wnsave;
}

// Fused leaky-relu + (N,16) x (16,64) FC for both tables. (unchanged)
__global__ __launch_bounds__(256) void k_fc(
    const float* __restrict__ upre, const float* __restrict__ ipre,
    const float* __restrict__ uw, const float* __restrict__ ub,
    const float* __restrict__ iw, const float* __restrict__ ib,
    float* __restrict__ out_u, float* __restrict__ out_i)
{
    const int tid = threadIdx.x;
    const int n = blockIdx.x * 4 + (tid >> 6);
    if (n >= NU + NM) return;
    const int o = tid & 63;
    const float* pre; const float* W; const float* B; float* dst;
    if (n < NU) { pre = upre + (size_t)n * 16; W = uw; B = ub; dst = out_u + (size_t)n * 64; }
    else { int n2 = n - NU; pre = ipre + (size_t)n2 * 16; W = iw; B = ib; dst = out_i + (size_t)n2 * 64; }
    float acc = B[o];
#pragma unroll
    for (int d = 0; d < 16; d++) {
        float x = pre[d];
        x = x >= 0.f ? x : 0.1f * x;
        acc += x * W[o * 16 + d];
    }
    dst[o] = acc;
}

extern "C" void kernel_launch(void* const* d_in, const int* in_sizes, int n_in,
                              void* d_out, int out_size, void* d_ws, size_t ws_size,
                              hipStream_t stream) {
    const float* ufk  = (const float*)d_in[0];
    const float* mfk  = (const float*)d_in[1];
    const float* ufs  = (const float*)d_in[2];
    const float* mfs  = (const float*)d_in[3];
    const float* rfe  = (const float*)d_in[4];
    const float* pro  = (const float*)d_in[5];
    const float* eta  = (const float*)d_in[6];
    const float* nwf  = (const float*)d_in[7];
    const float* rwf  = (const float*)d_in[8];
    const float* nwr  = (const float*)d_in[9];
    const float* rwr  = (const float*)d_in[10];
    const float* uw   = (const float*)d_in[11];
    const float* ub   = (const float*)d_in[12];
    const float* iw   = (const float*)d_in[13];
    const float* ib   = (const float*)d_in[14];
    const int*   eu   = (const int*)d_in[15];
    const int*   em   = (const int*)d_in[16];
    const int*   kp   = (const int*)d_in[17];

    float* out    = (float*)d_out;
    float* out_u  = out;                         // NU*64
    float* out_i  = out + (size_t)NU * 64;       // NM*64
    float* out_d  = out_i + (size_t)NM * 64;     // R*E

    float* ws    = (float*)d_ws;
    float* nrm_u = ws;                           // NU
    float* nrm_m = nrm_u + NU;                   // NM
    float* upre  = nrm_m + NM;                   // NU*16
    float* ipre  = upre + (size_t)NU * 16;       // NM*16
    float* wbuf  = ipre + (size_t)NM * 16;       // R*E
    uint*  msgP  = (uint*)(wbuf + (size_t)R_ * EDGES);  // R*E*16 uints = 32 MB (R15-proven budget)

    const size_t zeroN = (size_t)NU + NM + (size_t)NU * 16 + (size_t)NM * 16;
    hipMemsetAsync(d_ws, 0, zeroN * sizeof(float), stream);

    dim3 gW((EDGES + 15) / 16, R_);
    k_edge_w<<<gW, 256, 0, stream>>>(ufk, mfk, ufs, mfs, rfe, pro, eta, eu, em, kp,
                                     nwf, rwf, nwr, rwr, wbuf, nrm_u, nrm_m, msgP);
    dim3 gS(EDGES / 32, R_);
    k_scatter<<<gS, 256, 0, stream>>>(eu, em, wbuf, nrm_u, nrm_m, msgP,
                                      upre, ipre, out_d);
    k_fc<<<((NU + NM) + 3) / 4, 256, 0, stream>>>(upre, ipre, uw, ub, iw, ib, out_u, out_i);
}